// Round 13
// baseline (725.110 us; speedup 1.0000x reference)
//
#include <hip/hip_runtime.h>

// emb-lookup -> LSTM(64) over T=512 -> Dense(3) -> softmax.
// ONE WAVE (64 thr) PER SEQUENCE; 512 blocks x 64 thr; lane u owns unit u.
// R13: NO TABLE -- x-projection fused into the step with pinned fp16 Wk
// (64 regs) against the emb row, prefetched 2 steps ahead as RAW f32
// (cvt_pkrtz at consume time => vmcnt slack ~2 steps). x-dots are h-independent
// so they fill the issue slots that sat idle (VALUBusy 32%) during the DS
// round-trip + h-dot chain; separate accumulators px/ph keep x off the
// critical path. Removes build_table kernel (~70us) + 122 MB table traffic.
// h broadcast: wave-local LDS (single wave, in-order DS queue, no barrier);
// write->read gap filled with next-x prefetch work.
// (R5: v_pk_fma can't read AGPRs. R8: fp16 weights absmax 1.95e-3 ok.
//  R11: readlane broadcast = SALU-hazard swamp. R12: LDS rt beats readlane.)

#define VOCAB 50000
#define EMB 32
#define HID 64
#define NCLS 3
#define BATCH 512
#define TSEQ 512
#define FOURH 256
#define LOG2E 1.4426950408889634f

typedef _Float16 v2h __attribute__((ext_vector_type(2)));

__device__ __forceinline__ v2h bch(int i) { return __builtin_bit_cast(v2h, i); }
__device__ __forceinline__ int pkrtz(float a, float b) {
    return __builtin_bit_cast(int, __builtin_amdgcn_cvt_pkrtz(a, b));
}

#define PIN8(A, o) asm volatile("" : "+v"(A[o]), "+v"(A[o+1]), "+v"(A[o+2]), "+v"(A[o+3]), \
                                     "+v"(A[o+4]), "+v"(A[o+5]), "+v"(A[o+6]), "+v"(A[o+7]))

__device__ __forceinline__ float sigf(float z) {
    return __builtin_amdgcn_rcpf(1.0f + __builtin_amdgcn_exp2f(-LOG2E * z));
}
__device__ __forceinline__ float tanhf_fast(float z) {
    return fmaf(2.0f, __builtin_amdgcn_rcpf(1.0f + __builtin_amdgcn_exp2f(-2.0f * LOG2E * z)), -1.0f);
}

__global__ __launch_bounds__(64) __attribute__((amdgpu_waves_per_eu(1, 1)))
void lstm_kernel(const int* __restrict__ tokens, const float* __restrict__ emb,
                 const float* __restrict__ Wk, const float* __restrict__ Wr,
                 const float* __restrict__ bias, const float* __restrict__ Wd,
                 const float* __restrict__ bd, float* __restrict__ out)
{
    __shared__ __align__(16) int hlds[HID / 2];   // 64 fp16 = 128 B

    const int u   = threadIdx.x;        // hidden unit 0..63
    const int seq = blockIdx.x;
    const long tokbase = (long)seq * TSEQ;

    // recurrent weights: 4 gate cols x 32 k-pairs -> 128 half2 (int-packed)
    int wrh[4][32];
#pragma unroll
    for (int g = 0; g < 4; ++g) {
        const int cc = u + (g << 6);
#pragma unroll
        for (int m = 0; m < 32; ++m) {
            v2h t;
            t.x = (_Float16)Wr[(2 * m) * FOURH + cc];
            t.y = (_Float16)Wr[(2 * m + 1) * FOURH + cc];
            wrh[g][m] = __builtin_bit_cast(int, t);
        }
    }
    // input weights: 4 gate cols x 16 k-pairs -> 64 half2
    int wkh[4][16];
    float bmine[4];
#pragma unroll
    for (int g = 0; g < 4; ++g) {
        const int cc = u + (g << 6);
        bmine[g] = bias[cc];
#pragma unroll
        for (int m = 0; m < 16; ++m) {
            v2h t;
            t.x = (_Float16)Wk[(2 * m) * FOURH + cc];
            t.y = (_Float16)Wk[(2 * m + 1) * FOURH + cc];
            wkh[g][m] = __builtin_bit_cast(int, t);
        }
    }

    // x prefetch: raw f32 emb rows for t=0,1 (cvt deferred to consume time)
    float4 xraw[2][8];
    {
        const int t0 = tokens[tokbase], t1 = tokens[tokbase + 1];
        const float4* r0 = (const float4*)(emb + (long)t0 * EMB);
        const float4* r1 = (const float4*)(emb + (long)t1 * EMB);
#pragma unroll
        for (int m = 0; m < 8; ++m) { xraw[0][m] = r0[m]; xraw[1][m] = r1[m]; }
    }

    // h(0) = 0 into LDS (single wave: in-order DS queue, no barrier needed)
    ((_Float16*)hlds)[u] = (_Float16)0.0f;

    float c = 0.0f, h = 0.0f;

    for (int t = 0; t < TSEQ; ++t) {
        PIN8(wrh[0], 0); PIN8(wrh[0], 8); PIN8(wrh[0], 16); PIN8(wrh[0], 24);
        PIN8(wrh[1], 0); PIN8(wrh[1], 8); PIN8(wrh[1], 16); PIN8(wrh[1], 24);
        PIN8(wrh[2], 0); PIN8(wrh[2], 8); PIN8(wrh[2], 16); PIN8(wrh[2], 24);
        PIN8(wrh[3], 0); PIN8(wrh[3], 8); PIN8(wrh[3], 16); PIN8(wrh[3], 24);
        PIN8(wkh[0], 0); PIN8(wkh[0], 8);
        PIN8(wkh[1], 0); PIN8(wkh[1], 8);
        PIN8(wkh[2], 0); PIN8(wkh[2], 8);
        PIN8(wkh[3], 0); PIN8(wkh[3], 8);

        const int buf = t & 1;

        // broadcast h: 8 x ds_read_b128 (same addr all lanes = broadcast)
        int hp[32];
#pragma unroll
        for (int m = 0; m < 8; ++m) {
            const int4 r = ((const int4*)hlds)[m];
            hp[4 * m + 0] = r.x; hp[4 * m + 1] = r.y;
            hp[4 * m + 2] = r.z; hp[4 * m + 3] = r.w;
        }

        // x contribution (independent of h -> fills the DS/h-dot stall)
        int xh[16];
#pragma unroll
        for (int m = 0; m < 8; ++m) {
            const float4 r = xraw[buf][m];
            xh[2 * m + 0] = pkrtz(r.x, r.y);
            xh[2 * m + 1] = pkrtz(r.z, r.w);
        }
        float px0 = bmine[0], px1 = bmine[1], px2 = bmine[2], px3 = bmine[3];
#pragma unroll
        for (int m = 0; m < 16; ++m) {
            const v2h xm = bch(xh[m]);
            px0 = __builtin_amdgcn_fdot2(bch(wkh[0][m]), xm, px0, false);
            px1 = __builtin_amdgcn_fdot2(bch(wkh[1][m]), xm, px1, false);
            px2 = __builtin_amdgcn_fdot2(bch(wkh[2][m]), xm, px2, false);
            px3 = __builtin_amdgcn_fdot2(bch(wkh[3][m]), xm, px3, false);
        }

        float p0 = px0, p1 = px1, p2 = px2, p3 = px3;
#pragma unroll
        for (int m = 0; m < 32; ++m) {
            const v2h hm = bch(hp[m]);
            p0 = __builtin_amdgcn_fdot2(bch(wrh[0][m]), hm, p0, false);
            p1 = __builtin_amdgcn_fdot2(bch(wrh[1][m]), hm, p1, false);
            p2 = __builtin_amdgcn_fdot2(bch(wrh[2][m]), hm, p2, false);
            p3 = __builtin_amdgcn_fdot2(bch(wrh[3][m]), hm, p3, false);
        }

        const float gi = sigf(p0);
        const float gf = sigf(p1);
        const float gg = tanhf_fast(p2);
        const float go = sigf(p3);

        c = fmaf(gf, c, gi * gg);
        h = go * tanhf_fast(c);

        // publish h(t+1) (in-order DS queue: the reads above already retired)
        ((_Float16*)hlds)[u] = (_Float16)h;

        // refill x buffer for t+2 (fills the write->read gap; vmcnt slack 2 steps)
        {
            const int tn  = (t + 2 < TSEQ) ? t + 2 : TSEQ - 1;
            const int tok = tokens[tokbase + tn];
            const float4* rr = (const float4*)(emb + (long)tok * EMB);
#pragma unroll
            for (int m = 0; m < 8; ++m) xraw[buf][m] = rr[m];
        }
    }

    // Dense(3) + softmax: wave-wide butterfly reduction of h*Wd columns
    float pw0 = h * Wd[u * NCLS + 0];
    float pw1 = h * Wd[u * NCLS + 1];
    float pw2 = h * Wd[u * NCLS + 2];
#pragma unroll
    for (int k = 32; k >= 1; k >>= 1) {
        pw0 += __shfl_xor(pw0, k, 64);
        pw1 += __shfl_xor(pw1, k, 64);
        pw2 += __shfl_xor(pw2, k, 64);
    }
    if (u == 0) {
        const float l0 = pw0 + bd[0], l1 = pw1 + bd[1], l2 = pw2 + bd[2];
        const float mm = fmaxf(l0, fmaxf(l1, l2));
        const float e0 = __builtin_amdgcn_exp2f((l0 - mm) * LOG2E);
        const float e1 = __builtin_amdgcn_exp2f((l1 - mm) * LOG2E);
        const float e2 = __builtin_amdgcn_exp2f((l2 - mm) * LOG2E);
        const float inv = __builtin_amdgcn_rcpf(e0 + e1 + e2);
        out[seq * NCLS + 0] = e0 * inv;
        out[seq * NCLS + 1] = e1 * inv;
        out[seq * NCLS + 2] = e2 * inv;
    }
}

extern "C" void kernel_launch(void* const* d_in, const int* in_sizes, int n_in,
                              void* d_out, int out_size, void* d_ws, size_t ws_size,
                              hipStream_t stream) {
    const int*   tokens = (const int*)  d_in[0];
    const float* emb    = (const float*)d_in[1];
    const float* Wk     = (const float*)d_in[2];
    const float* Wr     = (const float*)d_in[3];
    const float* b      = (const float*)d_in[4];
    const float* Wd     = (const float*)d_in[5];
    const float* bd     = (const float*)d_in[6];
    float* out = (float*)d_out;

    lstm_kernel<<<dim3(BATCH), dim3(64), 0, stream>>>(
        tokens, emb, Wk, Wr, b, Wd, bd, out);
}